// Round 15
// baseline (270.496 us; speedup 1.0000x reference)
//
#include <hip/hip_runtime.h>
#include <math.h>

#define N_NODES 100000
#define N_EDGES 1600000
#define ROWB    512                 // bytes per row slot in d_out (legacy layout)
#define HALFB   51200000ull         // byte offset of second output (sigma half)
#define NBKT    196                 // sort buckets (512 dst nodes each)
#define BSH     9
#define BCAP    10240               // entries per bucket (mean 8192, >20 sigma margin)
#define EPB     1024                // edges per bin block
#define PREPB   384                 // prep_w blocks inside K1

typedef float  f32x4  __attribute__((ext_vector_type(4)));
typedef __bf16 bf16x8 __attribute__((ext_vector_type(8)));
typedef short  s16x8  __attribute__((ext_vector_type(8)));
typedef unsigned long long u64;

__device__ __forceinline__ unsigned short f2bf(float f) {
    unsigned int u = __builtin_bit_cast(unsigned int, f);
    u += 0x7FFFu + ((u >> 16) & 1u);          // RNE
    return (unsigned short)(u >> 16);
}
__device__ __forceinline__ float bf2f(unsigned short h) {
    unsigned int u = ((unsigned int)h) << 16;
    return __builtin_bit_cast(float, u);
}
__device__ __forceinline__ float bf_lo(unsigned int u) {
    return __builtin_bit_cast(float, u << 16);
}
__device__ __forceinline__ float bf_hi(unsigned int u) {
    return __builtin_bit_cast(float, u & 0xFFFF0000u);
}
__device__ __forceinline__ bf16x8 packhi(const float4& a, const float4& b) {
    float v[8] = {a.x, a.y, a.z, a.w, b.x, b.y, b.z, b.w};
    s16x8 hh;
    #pragma unroll
    for (int j = 0; j < 8; j++) hh[j] = (short)f2bf(v[j]);
    return __builtin_bit_cast(bf16x8, hh);
}
__device__ __forceinline__ void ntstore4(void* p, f32x4 v) {
    __builtin_nontemporal_store(v, (f32x4*)p);
}
__device__ __forceinline__ float fast_sp(float x) {
    return fmaxf(x, 0.f) + __logf(1.f + __expf(-fabsf(x))) + 1e-7f;
}

#define MFMA16(a, b, c) __builtin_amdgcn_mfma_f32_16x16x32_bf16((a), (b), (c), 0, 0, 0)

// ---------------- K1: prep_w (blocks 0..383) + bin (blocks 384..) -------------------

__launch_bounds__(256)
__global__ void k1_prep_bin(const float* __restrict__ W0, const float* __restrict__ Wmu,
                            const float* __restrict__ Wsig,
                            unsigned short* __restrict__ W0h, unsigned short* __restrict__ W0l,
                            unsigned short* __restrict__ Wmsh, unsigned short* __restrict__ Wmsl,
                            const int* __restrict__ row, const int* __restrict__ col,
                            int* __restrict__ gcur, u64* __restrict__ entries) {
    __shared__ int hist[NBKT], base[NBKT], cur[NBKT];
    const int tid = threadIdx.x;
    if (blockIdx.x < PREPB) {                    // ---- prep_w ----
        int c = blockIdx.x, k = tid;
        if (c < 128) {                           // W0 [256][128] -> [128 cols][256 k]
            float v = W0[k * 128 + c];
            unsigned short h = f2bf(v);
            W0h[c * 256 + k] = h;
            W0l[c * 256 + k] = f2bf(v - bf2f(h));
        } else if (k < 128) {                    // Wmu|Wsig -> [256 cols][128 k]
            int c2 = c - 128;
            float v = (c2 < 128) ? Wmu[k * 128 + c2] : Wsig[k * 128 + (c2 - 128)];
            unsigned short h = f2bf(v);
            Wmsh[c2 * 128 + k] = h;
            Wmsl[c2 * 128 + k] = f2bf(v - bf2f(h));
        }
        return;
    }
    // ---- bin ----
    const int bid = blockIdx.x - PREPB;
    for (int i = tid; i < NBKT; i += 256) { hist[i] = 0; cur[i] = 0; }
    __syncthreads();
    const int e0 = bid * EPB;
    int cols[4];
    #pragma unroll
    for (int it = 0; it < 4; it++) {
        int e = e0 + it * 256 + tid;
        int c = (e < N_EDGES) ? col[e] : -1;
        cols[it] = c;
        if (c >= 0) atomicAdd(&hist[c >> BSH], 1);
    }
    __syncthreads();
    for (int i = tid; i < NBKT; i += 256)
        base[i] = atomicAdd(&gcur[i], hist[i]);
    __syncthreads();
    #pragma unroll
    for (int it = 0; it < 4; it++) {
        int e = e0 + it * 256 + tid;
        int c = cols[it];
        if (c >= 0) {
            int b = c >> BSH;
            int r = atomicAdd(&cur[b], 1);
            entries[(size_t)b * BCAP + base[b] + r] =
                ((u64)(unsigned)c << 32) | (unsigned)row[e];
        }
    }
}

// ---------------- K2: csr (blocks 0..195, self-computed base) + gemm1 -----------------

__launch_bounds__(256, 3)
__global__ void k2_csr_gemm1(const u64* __restrict__ entries, const int* __restrict__ gcur,
                             int* __restrict__ cnt, int* __restrict__ offs,
                             float* __restrict__ dinv, int* __restrict__ sortedRow,
                             const float* __restrict__ x,
                             const unsigned short* __restrict__ Wh,
                             const unsigned short* __restrict__ Wl,
                             char* __restrict__ t0base, int t0stride) {
    __shared__ __align__(16) char L[49152];
    const int tid = threadIdx.x;

    if (blockIdx.x < NBKT) {                     // ---- csr ----
        int* lcnt = (int*)L;
        int* sA   = lcnt + 512;
        int* sB   = sA + 512;
        int* lcur = sB + 512;
        int* red  = lcur + 512;
        const int b = blockIdx.x, n0 = b << BSH;
        red[tid] = (tid < b) ? gcur[tid] : 0;
        __syncthreads();
        for (int d = 128; d > 0; d >>= 1) {
            if (tid < d) red[tid] += red[tid + d];
            __syncthreads();
        }
        const int base = red[0];
        const int nb = gcur[b];
        lcnt[tid] = 0; lcnt[tid + 256] = 0;
        __syncthreads();
        const u64* ep = entries + (size_t)b * BCAP;
        for (int i = tid; i < nb; i += 256)
            atomicAdd(&lcnt[(int)(ep[i] >> 32) - n0], 1);
        __syncthreads();
        sA[tid] = lcnt[tid]; sA[tid + 256] = lcnt[tid + 256];
        __syncthreads();
        int* src = sA; int* dst = sB;
        for (int d = 1; d < 512; d <<= 1) {
            #pragma unroll
            for (int k = tid; k < 512; k += 256)
                dst[k] = src[k] + ((k >= d) ? src[k - d] : 0);
            __syncthreads();
            int* t = src; src = dst; dst = t;
        }
        #pragma unroll
        for (int k = tid; k < 512; k += 256) {
            int excl = src[k] - lcnt[k];
            lcur[k] = excl;
            int node = n0 + k;
            if (node < N_NODES) {
                offs[node] = base + excl;
                cnt[node]  = lcnt[k];
                dinv[node] = rsqrtf((float)(lcnt[k] + 1));   // +1 self loop
            }
        }
        __syncthreads();
        for (int i = tid; i < nb; i += 256) {
            u64 pk = ep[i];
            int local = (int)(pk >> 32) - n0;
            int p = base + atomicAdd(&lcur[local], 1);
            sortedRow[p] = (int)(pk & 0xFFFFFFFFu);
        }
        return;
    }

    // ---- gemm1: 4 waves x 16 nodes (64 nodes/block) ----
    const int bid = blockIdx.x - NBKT;
    const int wave = tid >> 6, lane = tid & 63;
    const int lrow = lane & 15, q4 = lane >> 4;
    const int swz = (lrow & 7) << 4;
    const int n0 = bid * 64;

    bf16x8 b[8];
    {
        int node = n0 + wave * 16 + lrow;
        int nc = node > N_NODES - 1 ? N_NODES - 1 : node;
        const float* xp = x + (size_t)nc * 256 + q4 * 8;
        #pragma unroll
        for (int ks = 0; ks < 8; ks++) {
            float4 p0 = *(const float4*)(xp + ks * 32);
            float4 p1 = *(const float4*)(xp + ks * 32 + 4);
            b[ks] = packhi(p0, p1);
        }
    }

    int sgo[4], slo[4];
    #pragma unroll
    for (int j = 0; j < 4; j++) {
        int u = tid + 256 * j;
        int col = (u >> 5) & 15, k8 = (u & 31) * 8;
        sgo[j] = col * 256 + k8;
        slo[j] = (j >= 2 ? 8192 : 0) + ((col * 512 + k8 * 2) ^ ((col & 7) << 4));
    }

    {   // stage ct 0
        int4 sw[4];
        #pragma unroll
        for (int j = 0; j < 4; j++)
            sw[j] = *(const int4*)((j >= 2 ? Wl : Wh) + sgo[j]);
        #pragma unroll
        for (int j = 0; j < 4; j++)
            *(int4*)(L + slo[j]) = sw[j];
    }
    __syncthreads();

    #pragma unroll
    for (int ct = 0; ct < 8; ct++) {
        int4 sw[4];
        if (ct < 7) {
            #pragma unroll
            for (int j = 0; j < 4; j++)
                sw[j] = *(const int4*)((j >= 2 ? Wl : Wh) + (ct + 1) * 16 * 256 + sgo[j]);
        }
        const char* bufp = L + (ct & 1) * 16384;
        f32x4 acc = {};
        #pragma unroll
        for (int hl = 0; hl < 2; hl++) {
            bf16x8 w[8];
            #pragma unroll
            for (int ks = 0; ks < 8; ks++)
                w[ks] = *(const bf16x8*)(bufp + hl * 8192 +
                        ((lrow * 512 + ks * 64 + q4 * 16) ^ swz));
            #pragma unroll
            for (int ks = 0; ks < 8; ks++)
                acc = MFMA16(w[ks], b[ks], acc);
        }
        {
            int node_l = wave * 16 + lrow;
            int a = (node_l * 256 + ct * 32 + q4 * 8) ^ ((node_l & 7) << 4);
            ushort4 p = make_ushort4(f2bf(acc[0]), f2bf(acc[1]),
                                     f2bf(acc[2]), f2bf(acc[3]));
            *(ushort4*)(L + 32768 + a) = p;
        }
        if (ct < 7) {
            #pragma unroll
            for (int j = 0; j < 4; j++)
                *(int4*)(L + (((ct + 1) & 1) * 16384) + slo[j]) = sw[j];
            __syncthreads();
        }
    }
    __syncthreads();
    #pragma unroll
    for (int it = 0; it < 4; it++) {
        int linear = it * 4096 + tid * 16;
        int node_l = linear >> 8, off = linear & 255;
        int4 v = *(const int4*)(L + 32768 + (linear ^ ((node_l & 7) << 4)));
        int node = n0 + node_l;
        if (node < N_NODES)
            *(int4*)(t0base + (size_t)node * t0stride + off) = v;
    }
}

// ---------------- aggregation: 2 nodes/wave, scalarized 8-batches, idx prefetch --------
// Wave owns nodes nA,nB: two independent latency chains interleaved. Per batch:
// idx vector (prefetched) -> readlane -> 8 SGPR-base gathers; next batch's idx load
// issued while gathers are in flight. Uniform SGPR branches (no divergence).

template <int EPI>
__launch_bounds__(256)
__global__ void agg_bf16(const char* __restrict__ srcBase, char* __restrict__ dstBase,
                         int srcStride, int dstStride,
                         const int* __restrict__ offs, const int* __restrict__ cnt,
                         const int* __restrict__ sortedRow, const float* __restrict__ dinv,
                         const float* __restrict__ bias) {
    const int wv = threadIdx.x >> 6;
    const int lane = threadIdx.x & 63;
    const int l8 = lane & 7;
    const int laneB = lane * 4;
    const int nA = blockIdx.x * 8 + wv * 2;
    const int nB = nA + 1;

    // head loads, all issued up front
    const int startA = __builtin_amdgcn_readfirstlane(offs[nA]);
    const int numA   = __builtin_amdgcn_readfirstlane(cnt[nA]);
    const int startB = __builtin_amdgcn_readfirstlane(offs[nB]);
    const int numB   = __builtin_amdgcn_readfirstlane(cnt[nB]);
    int iacA = (numA > 0) ? (startA + (l8 < numA ? l8 : numA - 1)) : 0;
    int iacB = (numB > 0) ? (startB + (l8 < numB ? l8 : numB - 1)) : 0;
    int idxA = sortedRow[iacA];                  // first idx vectors in flight
    int idxB = sortedRow[iacB];
    const float dnA = dinv[nA], dnB = dinv[nB];
    unsigned int uA = *(const unsigned int*)(srcBase + (size_t)nA * srcStride + laneB);
    unsigned int uB = *(const unsigned int*)(srcBase + (size_t)nB * srcStride + laneB);
    float a0 = dnA * dnA * bf_lo(uA), a1 = dnA * dnA * bf_hi(uA);
    float b0 = dnB * dnB * bf_lo(uB), b1 = dnB * dnB * bf_hi(uB);

    const int mx = numA > numB ? numA : numB;
    for (int i = 0; i < mx; i += 8) {
        const bool doA = i < numA, doB = i < numB;     // wave-uniform
        int rsA[8], rsB[8];
        unsigned int ueA[8], ueB[8];
        if (doA) {
            #pragma unroll
            for (int j = 0; j < 8; j++) rsA[j] = __builtin_amdgcn_readlane(idxA, j);
            #pragma unroll
            for (int j = 0; j < 8; j++)
                ueA[j] = *(const unsigned int*)(srcBase + (size_t)rsA[j] * srcStride + laneB);
        }
        if (doB) {
            #pragma unroll
            for (int j = 0; j < 8; j++) rsB[j] = __builtin_amdgcn_readlane(idxB, j);
            #pragma unroll
            for (int j = 0; j < 8; j++)
                ueB[j] = *(const unsigned int*)(srcBase + (size_t)rsB[j] * srcStride + laneB);
        }
        // prefetch next idx vectors while gathers are in flight
        {
            int na = i + 8 + l8;
            int nb2 = i + 8 + l8;
            int pa = (numA > 0) ? (startA + (na < numA ? na : numA - 1)) : 0;
            int pb = (numB > 0) ? (startB + (nb2 < numB ? nb2 : numB - 1)) : 0;
            idxA = sortedRow[pa];
            idxB = sortedRow[pb];
        }
        if (doA) {
            float w[8];
            #pragma unroll
            for (int j = 0; j < 8; j++)
                w[j] = ((i + j) < numA) ? dnA * dinv[rsA[j]] : 0.f;
            #pragma unroll
            for (int j = 0; j < 8; j++) {
                a0 = fmaf(w[j], bf_lo(ueA[j]), a0);
                a1 = fmaf(w[j], bf_hi(ueA[j]), a1);
            }
        }
        if (doB) {
            float w[8];
            #pragma unroll
            for (int j = 0; j < 8; j++)
                w[j] = ((i + j) < numB) ? dnB * dinv[rsB[j]] : 0.f;
            #pragma unroll
            for (int j = 0; j < 8; j++) {
                b0 = fmaf(w[j], bf_lo(ueB[j]), b0);
                b1 = fmaf(w[j], bf_hi(ueB[j]), b1);
            }
        }
    }

    if (EPI) {
        float bv0 = bias[2 * lane], bv1 = bias[2 * lane + 1];
        a0 = fmaxf(a0 + bv0, 0.f); a1 = fmaxf(a1 + bv1, 0.f);
        b0 = fmaxf(b0 + bv0, 0.f); b1 = fmaxf(b1 + bv1, 0.f);
    }
    unsigned int oA = (unsigned int)f2bf(a0) | ((unsigned int)f2bf(a1) << 16);
    unsigned int oB = (unsigned int)f2bf(b0) | ((unsigned int)f2bf(b1) << 16);
    *(unsigned int*)(dstBase + (size_t)nA * dstStride + laneB) = oA;
    *(unsigned int*)(dstBase + (size_t)nB * dstStride + laneB) = oB;
}

// ---------------- GEMM2: SPLIT=1 -> one output half per block (needs t2 not in outc) ---

template <int SPLIT>
__launch_bounds__(256, 4)
__global__ void gemm2_mfma(const unsigned short* __restrict__ Wh,
                           const unsigned short* __restrict__ Wl,
                           const float* __restrict__ bmu, const float* __restrict__ bsig,
                           const char* __restrict__ t2base, int t2stride,
                           char* __restrict__ outc) {
    __shared__ __align__(16) char L[16384];
    const int tid = threadIdx.x;
    const int wave = tid >> 6, lane = tid & 63;
    const int lrow = lane & 15, q4 = lane >> 4;
    const int swz = (lrow & 7) << 4;
    const int half = SPLIT ? (blockIdx.x & 1) : 0;
    const int nb2  = SPLIT ? (blockIdx.x >> 1) : blockIdx.x;
    const int n0 = nb2 * 64;
    const int CT = SPLIT ? 8 : 16;

    const int node = n0 + wave * 16 + lrow;
    const bool ok = node < N_NODES;
    bf16x8 b[4];
    {
        int nc = node > N_NODES - 1 ? N_NODES - 1 : node;
        const char* ap = t2base + (size_t)nc * t2stride + q4 * 16;
        #pragma unroll
        for (int ki = 0; ki < 4; ki++)
            b[ki] = *(const bf16x8*)(ap + ki * 64);
    }

    const int colS = tid >> 4, k8S = (tid & 15) * 8;
    const int sgo = colS * 128 + k8S;
    const int sloc = (colS * 256 + k8S * 2) ^ ((colS & 7) << 4);
    const int g0 = half * 8;

    {   // stage tile g0
        int4 h = *(const int4*)(Wh + g0 * 2048 + sgo);
        int4 l = *(const int4*)(Wl + g0 * 2048 + sgo);
        *(int4*)(L + sloc) = h;
        *(int4*)(L + 4096 + sloc) = l;
    }
    __syncthreads();

    for (int ct = 0; ct < CT; ct++) {
        const int gct = g0 + ct;
        int4 swh, swl;
        if (ct < CT - 1) {
            swh = *(const int4*)(Wh + (gct + 1) * 2048 + sgo);
            swl = *(const int4*)(Wl + (gct + 1) * 2048 + sgo);
        }
        const char* bufp = L + (ct & 1) * 8192;
        f32x4 acc = {};
        #pragma unroll
        for (int hl = 0; hl < 2; hl++) {
            bf16x8 w[4];
            #pragma unroll
            for (int ki = 0; ki < 4; ki++)
                w[ki] = *(const bf16x8*)(bufp + hl * 4096 +
                        ((lrow * 256 + ki * 64 + q4 * 16) ^ swz));
            #pragma unroll
            for (int ki = 0; ki < 4; ki++)
                acc = MFMA16(w[ki], b[ki], acc);
        }
        const int f0 = (gct & 7) * 16 + q4 * 4;
        if (gct < 8) {                           // mu cols
            if (ok) {
                float4 bv = *(const float4*)(bmu + f0);
                f32x4 o = {acc[0] + bv.x, acc[1] + bv.y, acc[2] + bv.z, acc[3] + bv.w};
                ntstore4(outc + (size_t)node * ROWB + f0 * 4, o);
            }
        } else {                                 // sigma cols (fast softplus)
            if (ok) {
                float4 bv = *(const float4*)(bsig + f0);
                f32x4 o;
                #pragma unroll
                for (int q = 0; q < 4; q++)
                    o[q] = fast_sp(acc[q] + ((const float*)&bv)[q]);
                ntstore4(outc + HALFB + (size_t)node * ROWB + f0 * 4, o);
            }
        }
        if (ct < CT - 1) {
            char* nb = L + ((ct + 1) & 1) * 8192;
            *(int4*)(nb + sloc) = swh;
            *(int4*)(nb + 4096 + sloc) = swl;
            __syncthreads();
        }
    }
}

// ---------------- launch ----------------

extern "C" void kernel_launch(void* const* d_in, const int* in_sizes, int n_in,
                              void* d_out, int out_size, void* d_ws, size_t ws_size,
                              hipStream_t stream) {
    const float* x    = (const float*)d_in[0];
    const int*   ei   = (const int*)d_in[1];
    const int*   row  = ei;
    const int*   col  = ei + N_EDGES;
    const float* W0   = (const float*)d_in[2];
    const float* b0   = (const float*)d_in[3];
    const float* Wmu  = (const float*)d_in[4];
    const float* bmu  = (const float*)d_in[5];
    const float* Wsig = (const float*)d_in[6];
    const float* bsig = (const float*)d_in[7];
    char* outc = (char*)d_out;
    char* wsb  = (char*)d_ws;

    // tiered ws layout (256B-aligned fields); t2 placed early (cheapest dense win)
    size_t o = 0;
    auto take = [&](size_t nbytes) {
        size_t r = o; o += (nbytes + 255) & ~(size_t)255; return r;
    };
    size_t oW0h = take(65536), oW0l = take(65536);
    size_t oWmsh = take(65536), oWmsl = take(65536);
    size_t oGcur = take(NBKT * 4);
    size_t oCnt = take(N_NODES * 4), oOffs = take(N_NODES * 4), oDinv = take(N_NODES * 4);
    size_t oSort = take(N_EDGES * 4);
    size_t oT2 = take((size_t)N_NODES * 256);  size_t endT2 = o;   // ~33.5MB
    size_t oEnt = take((size_t)NBKT * BCAP * 8);
    size_t oT0 = take((size_t)N_NODES * 256);
    size_t oH  = take((size_t)N_NODES * 256);  size_t endAll = o;  // ~101MB
    const int tier = (ws_size >= endAll) ? 2 : (ws_size >= endT2 ? 1 : 0);

    unsigned short* W0h  = (unsigned short*)(wsb + oW0h);
    unsigned short* W0l  = (unsigned short*)(wsb + oW0l);
    unsigned short* Wmsh = (unsigned short*)(wsb + oWmsh);
    unsigned short* Wmsl = (unsigned short*)(wsb + oWmsl);
    int*   gcur      = (int*)(wsb + oGcur);
    int*   cnt       = (int*)(wsb + oCnt);
    int*   offs      = (int*)(wsb + oOffs);
    float* dinvp     = (float*)(wsb + oDinv);
    int*   sortedRow = (int*)(wsb + oSort);

    u64* entries = (tier == 2) ? (u64*)(wsb + oEnt) : (u64*)(outc + HALFB);
    char* t0b; int sT0;
    char* hb;  int sH;
    char* t2b; int sT2;
    if (tier == 2) { t0b = wsb + oT0; sT0 = 256; hb = wsb + oH; sH = 256; }
    else           { t0b = outc + 256; sT0 = ROWB; hb = outc + HALFB; sH = ROWB; }
    if (tier >= 1) { t2b = wsb + oT2; sT2 = 256; }
    else           { t2b = outc; sT2 = ROWB; }

    hipMemsetAsync(gcur, 0, NBKT * sizeof(int), stream);
    k1_prep_bin<<<PREPB + (N_EDGES + EPB - 1) / EPB, 256, 0, stream>>>(
        W0, Wmu, Wsig, W0h, W0l, Wmsh, Wmsl, row, col, gcur, entries);
    k2_csr_gemm1<<<NBKT + (N_NODES + 63) / 64, 256, 0, stream>>>(
        entries, gcur, cnt, offs, dinvp, sortedRow, x, W0h, W0l, t0b, sT0);
    agg_bf16<1><<<N_NODES / 8, 256, 0, stream>>>(t0b, hb, sT0, sH,
                                                 offs, cnt, sortedRow, dinvp, b0);
    agg_bf16<0><<<N_NODES / 8, 256, 0, stream>>>(hb, t2b, sH, sT2,
                                                 offs, cnt, sortedRow, dinvp, nullptr);
    if (tier >= 1)
        gemm2_mfma<1><<<2 * ((N_NODES + 63) / 64), 256, 0, stream>>>(
            Wmsh, Wmsl, bmu, bsig, t2b, sT2, outc);
    else
        gemm2_mfma<0><<<(N_NODES + 63) / 64, 256, 0, stream>>>(
            Wmsh, Wmsl, bmu, bsig, t2b, sT2, outc);
}

// Round 16
// 255.033 us; speedup vs baseline: 1.0606x; 1.0606x over previous
//
#include <hip/hip_runtime.h>
#include <math.h>

#define N_NODES 100000
#define N_EDGES 1600000
#define ROWB    512                 // bytes per row slot in d_out (legacy layout)
#define HALFB   51200000ull         // byte offset of second output (sigma half)
#define NBKT    196                 // sort buckets (512 dst nodes each)
#define BSH     9
#define BCAP    10240               // entries per bucket (mean 8192, >20 sigma margin)
#define EPB     1024                // edges per bin block
#define PREPB   384                 // prep_w blocks inside K1

typedef float  f32x4  __attribute__((ext_vector_type(4)));
typedef __bf16 bf16x8 __attribute__((ext_vector_type(8)));
typedef short  s16x8  __attribute__((ext_vector_type(8)));
typedef unsigned long long u64;

__device__ __forceinline__ unsigned short f2bf(float f) {
    unsigned int u = __builtin_bit_cast(unsigned int, f);
    u += 0x7FFFu + ((u >> 16) & 1u);          // RNE
    return (unsigned short)(u >> 16);
}
__device__ __forceinline__ float bf2f(unsigned short h) {
    unsigned int u = ((unsigned int)h) << 16;
    return __builtin_bit_cast(float, u);
}
__device__ __forceinline__ float bf_lo(unsigned int u) {
    return __builtin_bit_cast(float, u << 16);
}
__device__ __forceinline__ float bf_hi(unsigned int u) {
    return __builtin_bit_cast(float, u & 0xFFFF0000u);
}
__device__ __forceinline__ bf16x8 packhi(const float4& a, const float4& b) {
    float v[8] = {a.x, a.y, a.z, a.w, b.x, b.y, b.z, b.w};
    s16x8 hh;
    #pragma unroll
    for (int j = 0; j < 8; j++) hh[j] = (short)f2bf(v[j]);
    return __builtin_bit_cast(bf16x8, hh);
}
__device__ __forceinline__ void ntstore4(void* p, f32x4 v) {
    __builtin_nontemporal_store(v, (f32x4*)p);
}
__device__ __forceinline__ float fast_sp(float x) {
    return fmaxf(x, 0.f) + __logf(1.f + __expf(-fabsf(x))) + 1e-7f;
}

#define MFMA16(a, b, c) __builtin_amdgcn_mfma_f32_16x16x32_bf16((a), (b), (c), 0, 0, 0)

// ---------------- K1: prep_w (blocks 0..383) + bin (blocks 384..) -------------------

__launch_bounds__(256)
__global__ void k1_prep_bin(const float* __restrict__ W0, const float* __restrict__ Wmu,
                            const float* __restrict__ Wsig,
                            unsigned short* __restrict__ W0h, unsigned short* __restrict__ W0l,
                            unsigned short* __restrict__ Wmsh, unsigned short* __restrict__ Wmsl,
                            const int* __restrict__ row, const int* __restrict__ col,
                            int* __restrict__ gcur, u64* __restrict__ entries) {
    __shared__ int hist[NBKT], base[NBKT], cur[NBKT];
    const int tid = threadIdx.x;
    if (blockIdx.x < PREPB) {                    // ---- prep_w ----
        int c = blockIdx.x, k = tid;
        if (c < 128) {                           // W0 [256][128] -> [128 cols][256 k]
            float v = W0[k * 128 + c];
            unsigned short h = f2bf(v);
            W0h[c * 256 + k] = h;
            W0l[c * 256 + k] = f2bf(v - bf2f(h));
        } else if (k < 128) {                    // Wmu|Wsig -> [256 cols][128 k]
            int c2 = c - 128;
            float v = (c2 < 128) ? Wmu[k * 128 + c2] : Wsig[k * 128 + (c2 - 128)];
            unsigned short h = f2bf(v);
            Wmsh[c2 * 128 + k] = h;
            Wmsl[c2 * 128 + k] = f2bf(v - bf2f(h));
        }
        return;
    }
    // ---- bin ----
    const int bid = blockIdx.x - PREPB;
    for (int i = tid; i < NBKT; i += 256) { hist[i] = 0; cur[i] = 0; }
    __syncthreads();
    const int e0 = bid * EPB;
    int cols[4];
    #pragma unroll
    for (int it = 0; it < 4; it++) {
        int e = e0 + it * 256 + tid;
        int c = (e < N_EDGES) ? col[e] : -1;
        cols[it] = c;
        if (c >= 0) atomicAdd(&hist[c >> BSH], 1);
    }
    __syncthreads();
    for (int i = tid; i < NBKT; i += 256)
        base[i] = atomicAdd(&gcur[i], hist[i]);
    __syncthreads();
    #pragma unroll
    for (int it = 0; it < 4; it++) {
        int e = e0 + it * 256 + tid;
        int c = cols[it];
        if (c >= 0) {
            int b = c >> BSH;
            int r = atomicAdd(&cur[b], 1);
            entries[(size_t)b * BCAP + base[b] + r] =
                ((u64)(unsigned)c << 32) | (unsigned)row[e];
        }
    }
}

// ---------------- K2: csr (blocks 0..195, self-computed base) + gemm1 -----------------

__launch_bounds__(256, 3)
__global__ void k2_csr_gemm1(const u64* __restrict__ entries, const int* __restrict__ gcur,
                             int* __restrict__ cnt, int* __restrict__ offs,
                             float* __restrict__ dinv, int* __restrict__ sortedRow,
                             const float* __restrict__ x,
                             const unsigned short* __restrict__ Wh,
                             const unsigned short* __restrict__ Wl,
                             char* __restrict__ t0base, int t0stride) {
    __shared__ __align__(16) char L[49152];
    const int tid = threadIdx.x;

    if (blockIdx.x < NBKT) {                     // ---- csr ----
        int* lcnt = (int*)L;
        int* sA   = lcnt + 512;
        int* sB   = sA + 512;
        int* lcur = sB + 512;
        int* red  = lcur + 512;
        const int b = blockIdx.x, n0 = b << BSH;
        red[tid] = (tid < b) ? gcur[tid] : 0;
        __syncthreads();
        for (int d = 128; d > 0; d >>= 1) {
            if (tid < d) red[tid] += red[tid + d];
            __syncthreads();
        }
        const int base = red[0];
        const int nb = gcur[b];
        lcnt[tid] = 0; lcnt[tid + 256] = 0;
        __syncthreads();
        const u64* ep = entries + (size_t)b * BCAP;
        for (int i = tid; i < nb; i += 256)
            atomicAdd(&lcnt[(int)(ep[i] >> 32) - n0], 1);
        __syncthreads();
        sA[tid] = lcnt[tid]; sA[tid + 256] = lcnt[tid + 256];
        __syncthreads();
        int* src = sA; int* dst = sB;
        for (int d = 1; d < 512; d <<= 1) {
            #pragma unroll
            for (int k = tid; k < 512; k += 256)
                dst[k] = src[k] + ((k >= d) ? src[k - d] : 0);
            __syncthreads();
            int* t = src; src = dst; dst = t;
        }
        #pragma unroll
        for (int k = tid; k < 512; k += 256) {
            int excl = src[k] - lcnt[k];
            lcur[k] = excl;
            int node = n0 + k;
            if (node < N_NODES) {
                offs[node] = base + excl;
                cnt[node]  = lcnt[k];
                dinv[node] = rsqrtf((float)(lcnt[k] + 1));   // +1 self loop
            }
        }
        __syncthreads();
        for (int i = tid; i < nb; i += 256) {
            u64 pk = ep[i];
            int local = (int)(pk >> 32) - n0;
            int p = base + atomicAdd(&lcur[local], 1);
            sortedRow[p] = (int)(pk & 0xFFFFFFFFu);
        }
        return;
    }

    // ---- gemm1: 4 waves x 16 nodes (64 nodes/block) ----
    const int bid = blockIdx.x - NBKT;
    const int wave = tid >> 6, lane = tid & 63;
    const int lrow = lane & 15, q4 = lane >> 4;
    const int swz = (lrow & 7) << 4;
    const int n0 = bid * 64;

    bf16x8 b[8];
    {
        int node = n0 + wave * 16 + lrow;
        int nc = node > N_NODES - 1 ? N_NODES - 1 : node;
        const float* xp = x + (size_t)nc * 256 + q4 * 8;
        #pragma unroll
        for (int ks = 0; ks < 8; ks++) {
            float4 p0 = *(const float4*)(xp + ks * 32);
            float4 p1 = *(const float4*)(xp + ks * 32 + 4);
            b[ks] = packhi(p0, p1);
        }
    }

    int sgo[4], slo[4];
    #pragma unroll
    for (int j = 0; j < 4; j++) {
        int u = tid + 256 * j;
        int col = (u >> 5) & 15, k8 = (u & 31) * 8;
        sgo[j] = col * 256 + k8;
        slo[j] = (j >= 2 ? 8192 : 0) + ((col * 512 + k8 * 2) ^ ((col & 7) << 4));
    }

    {   // stage ct 0
        int4 sw[4];
        #pragma unroll
        for (int j = 0; j < 4; j++)
            sw[j] = *(const int4*)((j >= 2 ? Wl : Wh) + sgo[j]);
        #pragma unroll
        for (int j = 0; j < 4; j++)
            *(int4*)(L + slo[j]) = sw[j];
    }
    __syncthreads();

    #pragma unroll
    for (int ct = 0; ct < 8; ct++) {
        int4 sw[4];
        if (ct < 7) {
            #pragma unroll
            for (int j = 0; j < 4; j++)
                sw[j] = *(const int4*)((j >= 2 ? Wl : Wh) + (ct + 1) * 16 * 256 + sgo[j]);
        }
        const char* bufp = L + (ct & 1) * 16384;
        f32x4 acc = {};
        #pragma unroll
        for (int hl = 0; hl < 2; hl++) {
            bf16x8 w[8];
            #pragma unroll
            for (int ks = 0; ks < 8; ks++)
                w[ks] = *(const bf16x8*)(bufp + hl * 8192 +
                        ((lrow * 512 + ks * 64 + q4 * 16) ^ swz));
            #pragma unroll
            for (int ks = 0; ks < 8; ks++)
                acc = MFMA16(w[ks], b[ks], acc);
        }
        {
            int node_l = wave * 16 + lrow;
            int a = (node_l * 256 + ct * 32 + q4 * 8) ^ ((node_l & 7) << 4);
            ushort4 p = make_ushort4(f2bf(acc[0]), f2bf(acc[1]),
                                     f2bf(acc[2]), f2bf(acc[3]));
            *(ushort4*)(L + 32768 + a) = p;
        }
        if (ct < 7) {
            #pragma unroll
            for (int j = 0; j < 4; j++)
                *(int4*)(L + (((ct + 1) & 1) * 16384) + slo[j]) = sw[j];
            __syncthreads();
        }
    }
    __syncthreads();
    #pragma unroll
    for (int it = 0; it < 4; it++) {
        int linear = it * 4096 + tid * 16;
        int node_l = linear >> 8, off = linear & 255;
        int4 v = *(const int4*)(L + 32768 + (linear ^ ((node_l & 7) << 4)));
        int node = n0 + node_l;
        if (node < N_NODES)
            *(int4*)(t0base + (size_t)node * t0stride + off) = v;
    }
}

// ---------------- aggregation: 1 node/wave, scalarized 8-batches -----------------------
// MODE 0 (t0 -> h'): per-edge w = dn*dinv[r]; epilogue h' = dn * relu(acc + bias).
// MODE 1 (h' -> t2): input prescaled by dinv -> per-edge w = 1 (no dinv load);
//                    epilogue t2 = dn * acc.

template <int MODE>
__launch_bounds__(256)
__global__ void agg_bf16(const char* __restrict__ srcBase, char* __restrict__ dstBase,
                         int srcStride, int dstStride,
                         const int* __restrict__ offs, const int* __restrict__ cnt,
                         const int* __restrict__ sortedRow, const float* __restrict__ dinv,
                         const float* __restrict__ bias) {
    const int n = blockIdx.x * 4 + (threadIdx.x >> 6);
    const int lane = threadIdx.x & 63;
    const int laneB = lane * 4;
    const float dn = dinv[n];
    unsigned int u = *(const unsigned int*)(srcBase + (size_t)n * srcStride + laneB);
    const float ws = (MODE == 0) ? dn * dn : 1.f;   // MODE1 self: h'[n] has dn folded
    float acc0 = ws * bf_lo(u);
    float acc1 = ws * bf_hi(u);
    const int start = __builtin_amdgcn_readfirstlane(offs[n]);
    const int num   = __builtin_amdgcn_readfirstlane(cnt[n]);

    int i = 0;
    for (; i + 8 <= num; i += 8) {
        int myr = sortedRow[start + i + (lane & 7)];
        int rs[8];
        #pragma unroll
        for (int j = 0; j < 8; j++) rs[j] = __builtin_amdgcn_readlane(myr, j);
        unsigned int ue[8];
        #pragma unroll
        for (int j = 0; j < 8; j++) {
            const char* p = srcBase + (size_t)rs[j] * srcStride;   // SGPR base
            ue[j] = *(const unsigned int*)(p + laneB);
        }
        if (MODE == 0) {
            float w[8];
            #pragma unroll
            for (int j = 0; j < 8; j++) w[j] = dn * dinv[rs[j]];
            #pragma unroll
            for (int j = 0; j < 8; j++) {
                acc0 = fmaf(w[j], bf_lo(ue[j]), acc0);
                acc1 = fmaf(w[j], bf_hi(ue[j]), acc1);
            }
        } else {
            #pragma unroll
            for (int j = 0; j < 8; j++) {
                acc0 += bf_lo(ue[j]);
                acc1 += bf_hi(ue[j]);
            }
        }
    }
    for (; i < num; i++) {
        int rsv = __builtin_amdgcn_readfirstlane(sortedRow[start + i]);
        const char* p = srcBase + (size_t)rsv * srcStride;
        unsigned int ue = *(const unsigned int*)(p + laneB);
        if (MODE == 0) {
            float w = dn * dinv[rsv];
            acc0 = fmaf(w, bf_lo(ue), acc0);
            acc1 = fmaf(w, bf_hi(ue), acc1);
        } else {
            acc0 += bf_lo(ue);
            acc1 += bf_hi(ue);
        }
    }

    if (MODE == 0) {        // relu + bias, then prescale by dn for next layer
        acc0 = fmaxf(acc0 + bias[2 * lane], 0.f) * dn;
        acc1 = fmaxf(acc1 + bias[2 * lane + 1], 0.f) * dn;
    } else {                // final t2 = dn * acc
        acc0 *= dn;
        acc1 *= dn;
    }
    unsigned int o = (unsigned int)f2bf(acc0) | ((unsigned int)f2bf(acc1) << 16);
    *(unsigned int*)(dstBase + (size_t)n * dstStride + laneB) = o;
}

// ---------------- GEMM2: SPLIT=1 -> one output half per block (needs t2 not in outc) ---

template <int SPLIT>
__launch_bounds__(256, 4)
__global__ void gemm2_mfma(const unsigned short* __restrict__ Wh,
                           const unsigned short* __restrict__ Wl,
                           const float* __restrict__ bmu, const float* __restrict__ bsig,
                           const char* __restrict__ t2base, int t2stride,
                           char* __restrict__ outc) {
    __shared__ __align__(16) char L[16384];
    const int tid = threadIdx.x;
    const int wave = tid >> 6, lane = tid & 63;
    const int lrow = lane & 15, q4 = lane >> 4;
    const int swz = (lrow & 7) << 4;
    const int half = SPLIT ? (blockIdx.x & 1) : 0;
    const int nb2  = SPLIT ? (blockIdx.x >> 1) : blockIdx.x;
    const int n0 = nb2 * 64;
    const int CT = SPLIT ? 8 : 16;

    const int node = n0 + wave * 16 + lrow;
    const bool ok = node < N_NODES;
    bf16x8 b[4];
    {
        int nc = node > N_NODES - 1 ? N_NODES - 1 : node;
        const char* ap = t2base + (size_t)nc * t2stride + q4 * 16;
        #pragma unroll
        for (int ki = 0; ki < 4; ki++)
            b[ki] = *(const bf16x8*)(ap + ki * 64);
    }

    const int colS = tid >> 4, k8S = (tid & 15) * 8;
    const int sgo = colS * 128 + k8S;
    const int sloc = (colS * 256 + k8S * 2) ^ ((colS & 7) << 4);
    const int g0 = half * 8;

    {   // stage tile g0
        int4 h = *(const int4*)(Wh + g0 * 2048 + sgo);
        int4 l = *(const int4*)(Wl + g0 * 2048 + sgo);
        *(int4*)(L + sloc) = h;
        *(int4*)(L + 4096 + sloc) = l;
    }
    __syncthreads();

    for (int ct = 0; ct < CT; ct++) {
        const int gct = g0 + ct;
        int4 swh, swl;
        if (ct < CT - 1) {
            swh = *(const int4*)(Wh + (gct + 1) * 2048 + sgo);
            swl = *(const int4*)(Wl + (gct + 1) * 2048 + sgo);
        }
        const char* bufp = L + (ct & 1) * 8192;
        f32x4 acc = {};
        #pragma unroll
        for (int hl = 0; hl < 2; hl++) {
            bf16x8 w[4];
            #pragma unroll
            for (int ki = 0; ki < 4; ki++)
                w[ki] = *(const bf16x8*)(bufp + hl * 4096 +
                        ((lrow * 256 + ki * 64 + q4 * 16) ^ swz));
            #pragma unroll
            for (int ki = 0; ki < 4; ki++)
                acc = MFMA16(w[ki], b[ki], acc);
        }
        const int f0 = (gct & 7) * 16 + q4 * 4;
        if (gct < 8) {                           // mu cols
            if (ok) {
                float4 bv = *(const float4*)(bmu + f0);
                f32x4 o = {acc[0] + bv.x, acc[1] + bv.y, acc[2] + bv.z, acc[3] + bv.w};
                ntstore4(outc + (size_t)node * ROWB + f0 * 4, o);
            }
        } else {                                 // sigma cols (fast softplus)
            if (ok) {
                float4 bv = *(const float4*)(bsig + f0);
                f32x4 o;
                #pragma unroll
                for (int q = 0; q < 4; q++)
                    o[q] = fast_sp(acc[q] + ((const float*)&bv)[q]);
                ntstore4(outc + HALFB + (size_t)node * ROWB + f0 * 4, o);
            }
        }
        if (ct < CT - 1) {
            char* nb = L + ((ct + 1) & 1) * 8192;
            *(int4*)(nb + sloc) = swh;
            *(int4*)(nb + 4096 + sloc) = swl;
            __syncthreads();
        }
    }
}

// ---------------- launch ----------------

extern "C" void kernel_launch(void* const* d_in, const int* in_sizes, int n_in,
                              void* d_out, int out_size, void* d_ws, size_t ws_size,
                              hipStream_t stream) {
    const float* x    = (const float*)d_in[0];
    const int*   ei   = (const int*)d_in[1];
    const int*   row  = ei;
    const int*   col  = ei + N_EDGES;
    const float* W0   = (const float*)d_in[2];
    const float* b0   = (const float*)d_in[3];
    const float* Wmu  = (const float*)d_in[4];
    const float* bmu  = (const float*)d_in[5];
    const float* Wsig = (const float*)d_in[6];
    const float* bsig = (const float*)d_in[7];
    char* outc = (char*)d_out;
    char* wsb  = (char*)d_ws;

    // tiered ws layout (256B-aligned fields); t2 placed early (cheapest dense win)
    size_t o = 0;
    auto take = [&](size_t nbytes) {
        size_t r = o; o += (nbytes + 255) & ~(size_t)255; return r;
    };
    size_t oW0h = take(65536), oW0l = take(65536);
    size_t oWmsh = take(65536), oWmsl = take(65536);
    size_t oGcur = take(NBKT * 4);
    size_t oCnt = take(N_NODES * 4), oOffs = take(N_NODES * 4), oDinv = take(N_NODES * 4);
    size_t oSort = take(N_EDGES * 4);
    size_t oT2 = take((size_t)N_NODES * 256);  size_t endT2 = o;   // ~33.5MB
    size_t oEnt = take((size_t)NBKT * BCAP * 8);
    size_t oT0 = take((size_t)N_NODES * 256);
    size_t oH  = take((size_t)N_NODES * 256);  size_t endAll = o;  // ~101MB
    const int tier = (ws_size >= endAll) ? 2 : (ws_size >= endT2 ? 1 : 0);

    unsigned short* W0h  = (unsigned short*)(wsb + oW0h);
    unsigned short* W0l  = (unsigned short*)(wsb + oW0l);
    unsigned short* Wmsh = (unsigned short*)(wsb + oWmsh);
    unsigned short* Wmsl = (unsigned short*)(wsb + oWmsl);
    int*   gcur      = (int*)(wsb + oGcur);
    int*   cnt       = (int*)(wsb + oCnt);
    int*   offs      = (int*)(wsb + oOffs);
    float* dinvp     = (float*)(wsb + oDinv);
    int*   sortedRow = (int*)(wsb + oSort);

    u64* entries = (tier == 2) ? (u64*)(wsb + oEnt) : (u64*)(outc + HALFB);
    char* t0b; int sT0;
    char* hb;  int sH;
    char* t2b; int sT2;
    if (tier == 2) { t0b = wsb + oT0; sT0 = 256; hb = wsb + oH; sH = 256; }
    else           { t0b = outc + 256; sT0 = ROWB; hb = outc + HALFB; sH = ROWB; }
    if (tier >= 1) { t2b = wsb + oT2; sT2 = 256; }
    else           { t2b = outc; sT2 = ROWB; }

    hipMemsetAsync(gcur, 0, NBKT * sizeof(int), stream);
    k1_prep_bin<<<PREPB + (N_EDGES + EPB - 1) / EPB, 256, 0, stream>>>(
        W0, Wmu, Wsig, W0h, W0l, Wmsh, Wmsl, row, col, gcur, entries);
    k2_csr_gemm1<<<NBKT + (N_NODES + 63) / 64, 256, 0, stream>>>(
        entries, gcur, cnt, offs, dinvp, sortedRow, x, W0h, W0l, t0b, sT0);
    agg_bf16<0><<<N_NODES / 4, 256, 0, stream>>>(t0b, hb, sT0, sH,
                                                 offs, cnt, sortedRow, dinvp, b0);
    agg_bf16<1><<<N_NODES / 4, 256, 0, stream>>>(hb, t2b, sH, sT2,
                                                 offs, cnt, sortedRow, dinvp, nullptr);
    if (tier >= 1)
        gemm2_mfma<1><<<2 * ((N_NODES + 63) / 64), 256, 0, stream>>>(
            Wmsh, Wmsl, bmu, bsig, t2b, sT2, outc);
    else
        gemm2_mfma<0><<<(N_NODES + 63) / 64, 256, 0, stream>>>(
            Wmsh, Wmsl, bmu, bsig, t2b, sT2, outc);
}